// Round 7
// baseline (133.398 us; speedup 1.0000x reference)
//
#include <hip/hip_runtime.h>
#include <math.h>

typedef __attribute__((ext_vector_type(8))) _Float16 half8;
typedef __attribute__((ext_vector_type(4))) _Float16 half4;
typedef __attribute__((ext_vector_type(4))) float    f32x4;
typedef __attribute__((ext_vector_type(2))) float    f32x2;

#define TSTEPS 28
#define IDIM   28
#define HDIM   128
#define NKC    5       // K chunks of 32: 160 = 128 (h) + 28 (x) + bias(1) + 3 pad
#define TILE_B 32      // two 16-row streams per block
#define CDIM   10

#if __has_builtin(__builtin_amdgcn_exp2f)
#define EXP2F(x) __builtin_amdgcn_exp2f(x)
#else
#define EXP2F(x) exp2f(x)
#endif
#if __has_builtin(__builtin_amdgcn_rcpf)
#define RCPF(x) __builtin_amdgcn_rcpf(x)
#else
#define RCPF(x) (1.0f / (x))
#endif

#define NLOG2E (-1.44269504f)
#define P2LOG2E (2.88539008f)

#define MFMA16(a,b,c) __builtin_amdgcn_mfma_f32_16x16x32_f16((a),(b),(c),0,0,0)

// P[kc][gate][n8][lane][j] (f16): B-fragment order for mfma_f32_16x16x32_f16.
// Activation scales folded (i,f,o x -log2e; g x 2log2e). Bias row at k=156
// (pairs with constant 1.0 in A column 156). k=157..159 zero.
__global__ __launch_bounds__(256) void pack_w(const float* __restrict__ Wih,
                                              const float* __restrict__ Whh,
                                              const float* __restrict__ bih,
                                              const float* __restrict__ bhh,
                                              _Float16* __restrict__ P) {
    int e = blockIdx.x * 256 + threadIdx.x;      // 5*4*8*64*8 = 81920
    if (e >= NKC * 4 * 8 * 64 * 8) return;
    int j  = e & 7;
    int ln = (e >> 3) & 63;
    int w  = (e >> 9) & 7;
    int t  = (e >> 12) & 3;
    int kc = e >> 14;
    int k  = kc * 32 + ((ln >> 4) << 3) + j;
    int u  = w * 16 + (ln & 15);
    int g  = t * HDIM + u;
    float v = 0.f;
    if (k < HDIM)                   v = Whh[g * HDIM + k];
    else if (k < HDIM + IDIM)       v = Wih[g * IDIM + (k - HDIM)];
    else if (k == HDIM + IDIM)      v = bih[g] + bhh[g];   // bias row
    float sc = (t == 2) ? P2LOG2E : NLOG2E;
    P[e] = (_Float16)(v * sc);
}

// 16 waves / 1024 threads / 1 block per CU -> 4 waves per SIMD
// (per SIMD: 2 stream-A waves + 2 stream-B waves, roles anti-phased).
// R7 changes vs R6 (both target the ~1500 cyc/interval no-issue gap whose
// accounting matches act-waves and MFMA-waves NOT overlapping):
//  1. s_setprio REMOVED: prio-1 MFMA waves starved co-resident act waves
//     of issue slots (serialized the roles). Evidence: R0 (no setprio)
//     61.6us; R3-R6 (setprio) 62-67us; m190 setprio negative on lockstep.
//  2. x(t+1) load issued at the TOP of the wave's MFMA phase (previous
//     interval), so the vmcnt(0)-before-barrier drain is covered by the
//     whole MFMA interval instead of tail-stalling the act phase.
__global__ __launch_bounds__(1024, 4) void lstm_kernel(
    const float* __restrict__ x,          // [B][28][28] fp32
    const _Float16* __restrict__ P,       // packed weights, 160 KB
    const float* __restrict__ Wfc,        // [10][128]
    const float* __restrict__ b_fc,       // [10]
    float* __restrict__ out)              // [B][10]
{
    __shared__ __align__(16) _Float16 frag[2][4][64][8];       // 8 KB (h planes)
    __shared__ __align__(16) _Float16 Plds[4][8][64][8];       // 32 KB (kc4 B-frags)
    __shared__ __align__(16) float hplain[TILE_B][HDIM + 4];   // 16.9 KB

    const int tid = threadIdx.x;               // 0..1023
    const int l   = tid & 63;
    const int w   = tid >> 6;                  // wave 0..15
    const int sid = w >> 3;                    // stream 0 (A) / 1 (B)
    const int w8  = w & 7;                     // col-tile index in stream
    const int b0  = blockIdx.x * TILE_B;

    // ---- stage kc4 B-frags into LDS: 2048 float4 by 1024 threads ----
    {
        const float4* P4 = (const float4*)P;
        float4* dst = (float4*)Plds;
        dst[tid]        = P4[8192 + tid];
        dst[tid + 1024] = P4[9216 + tid];
    }
    // ---- h-part B-frags in regs: breg[gate][kc], 16 half8 ----
    half8 breg[4][4];
    {
        const half8* Pp = (const half8*)P;
        #pragma unroll
        for (int kc = 0; kc < 4; ++kc)
            #pragma unroll
            for (int g = 0; g < 4; ++g)
                breg[g][kc] = Pp[((kc * 4 + g) * 8 + w8) * 64 + l];
    }

    // ---- init LDS: zero h planes of both streams (h(-1) = 0) ----
    {
        float4 z = {0.f, 0.f, 0.f, 0.f};
        if (tid < 512) ((float4*)frag)[tid] = z;   // 8 KB = 512 float4
    }

    const int l15 = l & 15;
    const int u    = w8 * 16 + l15;                // owned gate-col
    const int kc_h = w8 >> 1;                      // u>>5 (wave-uniform)
    const int quad = (2 * w8 + ((l >> 3) & 1)) & 3;
    const int jh   = l & 7;
    const int mb   = (l >> 4) << 2;                // row base for C-layout
    _Float16 (*myfrag)[64][8] = frag[sid];

    // x A-frag source: lane l = row (l&15), k-cols 8*(l>>4) .. +8 of x(t).
    // cols 0..27 are x; col 28 (k=156) is the bias-1.0; 29..31 zero.
    const float* xp = x + (size_t)(b0 + sid * 16 + l15) * (TSTEPS * IDIM)
                        + 8 * (l >> 4);
    const int o2 = (l < 48) ? 4 : 0;           // 2nd float4 (lanes>=48: dummy)

    f32x4 acc[4];                              // one 16x16 tile per gate
    f32x2 cst01 = {0.f, 0.f}, cst23 = {0.f, 0.f};
    const f32x4 zc = {0.f, 0.f, 0.f, 0.f};
    half8 a4;                                  // current x A-frag (regs)
    float4 xv0, xv1;                           // in-flight x(t+1) (regs)

    auto cvt_a4 = [&](float4 v0, float4 v1) {
        if (l >= 48) v1 = (float4){1.f, 0.f, 0.f, 0.f};   // bias col
        half8 r;
        r[0] = (_Float16)v0.x; r[1] = (_Float16)v0.y;
        r[2] = (_Float16)v0.z; r[3] = (_Float16)v0.w;
        r[4] = (_Float16)v1.x; r[5] = (_Float16)v1.y;
        r[6] = (_Float16)v1.z; r[7] = (_Float16)v1.w;
        a4 = r;
    };

    // prologue: x(0) A-frag for all waves
    cvt_a4(*(const float4*)(xp), *(const float4*)(xp + o2));

    // ---- MFMA role: issue x(t+1) load first; gates(t) = W.[h(t-1),x(t),1] ----
    auto mfma_phase = [&](int t) {
        if (t + 1 < TSTEPS) {                  // in flight across this interval
            xv0 = *(const float4*)(xp + (t + 1) * IDIM);
            xv1 = *(const float4*)(xp + (t + 1) * IDIM + o2);
        }
        half8 A0 = *(const half8*)&myfrag[0][l][0];
        half8 A1 = *(const half8*)&myfrag[1][l][0];
        half8 A2 = *(const half8*)&myfrag[2][l][0];
        half8 A3 = *(const half8*)&myfrag[3][l][0];
        #pragma unroll
        for (int g = 0; g < 4; ++g) {          // kc4: x + bias init
            half8 pb = *(const half8*)&Plds[g][w8][l][0];
            acc[g] = MFMA16(a4, pb, zc);
        }
        #pragma unroll
        for (int g = 0; g < 4; ++g) acc[g] = MFMA16(A0, breg[g][0], acc[g]);
        #pragma unroll
        for (int g = 0; g < 4; ++g) acc[g] = MFMA16(A1, breg[g][1], acc[g]);
        #pragma unroll
        for (int g = 0; g < 4; ++g) acc[g] = MFMA16(A2, breg[g][2], acc[g]);
        #pragma unroll
        for (int g = 0; g < 4; ++g) acc[g] = MFMA16(A3, breg[g][3], acc[g]);
    };

    // ---- act role: 4 h/lane; h -> own kc chunk; cvt prefetched x(t+1) ----
    auto act_phase = [&](int t) {
        const bool lastT = (t == TSTEPS - 1);
        float hv[4];
        #pragma unroll
        for (int rp = 0; rp < 2; ++rp) {
            const int r0 = rp * 2, r1 = r0 + 1;
            f32x2 Ei = {EXP2F(acc[0][r0]), EXP2F(acc[0][r1])};   // e^{-i}
            f32x2 Ef = {EXP2F(acc[1][r0]), EXP2F(acc[1][r1])};   // e^{-f}
            f32x2 Eg = {EXP2F(acc[2][r0]), EXP2F(acc[2][r1])};   // e^{2g}
            f32x2 Eo = {EXP2F(acc[3][r0]), EXP2F(acc[3][r1])};   // e^{-o}
            f32x2 one = {1.f, 1.f};
            f32x2 Di = Ei + one, Df = Ef + one, Dg = Eg + one, Do = Eo + one;
            f32x2 Pif = Di * Df, Pgo = Dg * Do;
            f32x2 Rif = {RCPF(Pif.x), RCPF(Pif.y)};
            f32x2 Rgo = {RCPF(Pgo.x), RCPF(Pgo.y)};
            f32x2 is = Rif * Df, fs = Rif * Di;
            f32x2 gt = one - 2.f * (Rgo * Do);
            f32x2 os = Rgo * Dg;
            f32x2 cstp = rp ? cst23 : cst01;
            f32x2 c = fs * cstp + is * gt;
            if (rp) cst23 = c; else cst01 = c;
            f32x2 Etc = {EXP2F(c.x * P2LOG2E), EXP2F(c.y * P2LOG2E)};
            f32x2 Dtc = Etc + one;
            f32x2 Rtc = {RCPF(Dtc.x), RCPF(Dtc.y)};
            f32x2 tc = one - 2.f * Rtc;
            f32x2 h2 = os * tc;
            hv[r0] = h2.x; hv[r1] = h2.y;
        }
        if (lastT) {
            #pragma unroll
            for (int r = 0; r < 4; ++r)
                hplain[sid * 16 + mb + r][u] = hv[r];
        } else {
            #pragma unroll
            for (int r = 0; r < 4; ++r)
                myfrag[kc_h][mb + r + 16 * quad][jh] = (_Float16)hv[r];
            cvt_a4(xv0, xv1);                  // a4 <- x(t+1) fragment
        }
    };

    __syncthreads();

    // phase 0: stream A computes gates(0); B idles (enters loop in MFMA role)
    if (sid == 0) mfma_phase(0);
    __syncthreads();

    for (int t = 0; t < TSTEPS; ++t) {
        // odd phase: A act(t) || B MFMA(t)
        if (sid == 0) act_phase(t);
        else          mfma_phase(t);
        __syncthreads();
        // even phase: A MFMA(t+1) || B act(t)
        if (sid == 0) { if (t + 1 < TSTEPS) mfma_phase(t + 1); }
        else          act_phase(t);
        __syncthreads();
    }

    // ---- FC + ReLU epilogue ----
    if (tid < TILE_B * CDIM) {
        int row = tid / CDIM, c = tid % CDIM;
        const float4* hv4 = (const float4*)&hplain[row][0];
        const float4* wf  = (const float4*)(Wfc + c * HDIM);
        float s = b_fc[c];
        #pragma unroll
        for (int q = 0; q < 32; ++q) {
            float4 a4v = hv4[q], b4 = wf[q];
            s += a4v.x * b4.x + a4v.y * b4.y + a4v.z * b4.z + a4v.w * b4.w;
        }
        out[(size_t)(b0 + row) * CDIM + c] = fmaxf(s, 0.f);
    }
}

extern "C" void kernel_launch(void* const* d_in, const int* in_sizes, int n_in,
                              void* d_out, int out_size, void* d_ws, size_t ws_size,
                              hipStream_t stream) {
    const float* x   = (const float*)d_in[0];
    const float* Wih = (const float*)d_in[1];
    const float* Whh = (const float*)d_in[2];
    const float* bih = (const float*)d_in[3];
    const float* bhh = (const float*)d_in[4];
    const float* Wfc = (const float*)d_in[5];
    const float* bfc = (const float*)d_in[6];
    float* out = (float*)d_out;
    _Float16* P = (_Float16*)d_ws;     // 160 KB packed weights

    hipLaunchKernelGGL(pack_w, dim3(320), dim3(256), 0, stream, Wih, Whh, bih, bhh, P);
    hipLaunchKernelGGL(lstm_kernel, dim3(8192 / TILE_B), dim3(1024), 0, stream,
                       x, P, Wfc, bfc, out);
}

// Round 8
// 124.525 us; speedup vs baseline: 1.0713x; 1.0713x over previous
//
#include <hip/hip_runtime.h>
#include <math.h>

typedef __attribute__((ext_vector_type(8))) _Float16 half8;
typedef __attribute__((ext_vector_type(4))) _Float16 half4;
typedef __attribute__((ext_vector_type(4))) float    f32x4;
typedef __attribute__((ext_vector_type(2))) float    f32x2;

#define TSTEPS 28
#define IDIM   28
#define HDIM   128
#define NKC    5       // K chunks of 32: 160 = 128 (h) + 28 (x) + bias(1) + 3 pad
#define TILE_B 32      // two 16-row groups per block
#define CDIM   10

#if __has_builtin(__builtin_amdgcn_exp2f)
#define EXP2F(x) __builtin_amdgcn_exp2f(x)
#else
#define EXP2F(x) exp2f(x)
#endif
#if __has_builtin(__builtin_amdgcn_rcpf)
#define RCPF(x) __builtin_amdgcn_rcpf(x)
#else
#define RCPF(x) (1.0f / (x))
#endif

#define NLOG2E (-1.44269504f)
#define P2LOG2E (2.88539008f)

#define MFMA16(a,b,c) __builtin_amdgcn_mfma_f32_16x16x32_f16((a),(b),(c),0,0,0)

// P[kc][gate][n8][lane][j] (f16): B-fragment order for mfma_f32_16x16x32_f16.
// Activation scales folded (i,f,o x -log2e; g x 2log2e). Bias row at k=156
// (pairs with constant 1.0 in A column 156). k=157..159 zero.
__global__ __launch_bounds__(256) void pack_w(const float* __restrict__ Wih,
                                              const float* __restrict__ Whh,
                                              const float* __restrict__ bih,
                                              const float* __restrict__ bhh,
                                              _Float16* __restrict__ P) {
    int e = blockIdx.x * 256 + threadIdx.x;      // 5*4*8*64*8 = 81920
    if (e >= NKC * 4 * 8 * 64 * 8) return;
    int j  = e & 7;
    int ln = (e >> 3) & 63;
    int w  = (e >> 9) & 7;
    int t  = (e >> 12) & 3;
    int kc = e >> 14;
    int k  = kc * 32 + ((ln >> 4) << 3) + j;
    int u  = w * 16 + (ln & 15);
    int g  = t * HDIM + u;
    float v = 0.f;
    if (k < HDIM)                   v = Whh[g * HDIM + k];
    else if (k < HDIM + IDIM)       v = Wih[g * IDIM + (k - HDIM)];
    else if (k == HDIM + IDIM)      v = bih[g] + bhh[g];   // bias row
    float sc = (t == 2) ? P2LOG2E : NLOG2E;
    P[e] = (_Float16)(v * sc);
}

// 16 waves / 1024 threads / 1 block per CU -> 4 waves per SIMD.
// Row groups: waves 0-7 = rows 0..15, waves 8-15 = rows 16..31. Each wave
// owns 16 gate-cols of all four gates (act fully lane-local).
//
// R8: ONE barrier interval per step (was 2 with role anti-phasing).
// Every wave does {A-frag reads, 20 MFMAs kc-outer, issue x(t+1), act,
// h -> OTHER h-buffer, cvt} then one __syncthreads. Correctness via
// double-buffered h planes (read buf t&1, write buf (t+1)&1 -- R0's
// scheme). Rationale: all spill-free 4-wave variants sit at 61.6-62.5us
// with ~1300 cyc/interval unattributed overhead that scales with
// INTERVAL COUNT (barrier convoy: 16-wave ds_read burst + ramp/drain),
// not with work. Halving intervals (57 -> 28) halves that overhead.
// x loads issued AFTER the MFMA cluster (R7 lesson: any value alive
// across the MFMAs spills past the 128-reg cap).
__global__ __launch_bounds__(1024, 4) void lstm_kernel(
    const float* __restrict__ x,          // [B][28][28] fp32
    const _Float16* __restrict__ P,       // packed weights, 160 KB
    const float* __restrict__ Wfc,        // [10][128]
    const float* __restrict__ b_fc,       // [10]
    float* __restrict__ out)              // [B][10]
{
    // h A-frag planes, double-buffered per group: [buf][grp][kc][slot][j]
    __shared__ __align__(16) _Float16 frag[2][2][4][64][8];    // 16 KB
    // Plds (kc4 B-frags, 32 KB) unioned with hplain (16.9 KB): Plds is
    // dead after the last in-loop barrier; hplain written only after it.
    __shared__ __align__(16) char ubuf[4 * 8 * 64 * 8 * 2];    // 32 KB
    _Float16 (*Plds)[8][64][8] = (_Float16 (*)[8][64][8])ubuf;
    float (*hplain)[HDIM + 4]  = (float (*)[HDIM + 4])ubuf;

    const int tid = threadIdx.x;               // 0..1023
    const int l   = tid & 63;
    const int w   = tid >> 6;                  // wave 0..15
    const int grp = w >> 3;                    // row group 0/1
    const int w8  = w & 7;                     // col-tile index in group
    const int b0  = blockIdx.x * TILE_B;

    // ---- stage kc4 B-frags into LDS: 2048 float4 by 1024 threads ----
    {
        const float4* P4 = (const float4*)P;
        float4* dst = (float4*)ubuf;
        dst[tid]        = P4[8192 + tid];
        dst[tid + 1024] = P4[9216 + tid];
    }
    // ---- h-part B-frags in regs: breg[gate][kc], 16 half8 ----
    half8 breg[4][4];
    {
        const half8* Pp = (const half8*)P;
        #pragma unroll
        for (int kc = 0; kc < 4; ++kc)
            #pragma unroll
            for (int g = 0; g < 4; ++g)
                breg[g][kc] = Pp[((kc * 4 + g) * 8 + w8) * 64 + l];
    }

    // ---- init LDS: zero buffer-0 h planes of both groups (h(-1)=0) ----
    {
        float4 z = {0.f, 0.f, 0.f, 0.f};
        if (tid < 512) ((float4*)frag)[tid] = z;   // frag[0] = 8 KB
    }

    const int l15 = l & 15;
    const int u    = w8 * 16 + l15;                // owned gate-col
    const int kc_h = w8 >> 1;                      // u>>5 (wave-uniform)
    const int quad = (2 * w8 + ((l >> 3) & 1)) & 3;
    const int jh   = l & 7;
    const int mb   = (l >> 4) << 2;                // row base for C-layout

    // x A-frag source: lane l = row (l&15), k-cols 8*(l>>4) .. +8 of x(t).
    // cols 0..27 are x; col 28 (k=156) is the bias-1.0; 29..31 zero.
    const float* xp = x + (size_t)(b0 + grp * 16 + l15) * (TSTEPS * IDIM)
                        + 8 * (l >> 4);
    const int o2 = (l < 48) ? 4 : 0;           // 2nd float4 (lanes>=48: dummy)

    f32x2 cst01 = {0.f, 0.f}, cst23 = {0.f, 0.f};
    const f32x4 zc = {0.f, 0.f, 0.f, 0.f};
    half8 a4;                                  // current x A-frag (regs)
    float hv[4];                               // last act output (epilogue)

    auto cvt_a4 = [&](float4 v0, float4 v1) {
        if (l >= 48) v1 = (float4){1.f, 0.f, 0.f, 0.f};   // bias col
        half8 r;
        r[0] = (_Float16)v0.x; r[1] = (_Float16)v0.y;
        r[2] = (_Float16)v0.z; r[3] = (_Float16)v0.w;
        r[4] = (_Float16)v1.x; r[5] = (_Float16)v1.y;
        r[6] = (_Float16)v1.z; r[7] = (_Float16)v1.w;
        a4 = r;
    };

    // prologue: x(0) A-frag for all waves
    cvt_a4(*(const float4*)(xp), *(const float4*)(xp + o2));

    __syncthreads();

    for (int t = 0; t < TSTEPS; ++t) {
        const _Float16 (*cur)[64][8] = frag[t & 1][grp];
        _Float16 (*nxt)[64][8]       = frag[(t + 1) & 1][grp];
        const bool more = (t + 1 < TSTEPS);

        // ---- MFMA: gates(t) = W.[h(t-1), x(t), 1], kc-outer ----
        half8 A0 = *(const half8*)&cur[0][l][0];
        half8 A1 = *(const half8*)&cur[1][l][0];
        half8 A2 = *(const half8*)&cur[2][l][0];
        half8 A3 = *(const half8*)&cur[3][l][0];
        f32x4 acc[4];
        #pragma unroll
        for (int g = 0; g < 4; ++g) {          // kc4: x + bias init
            half8 pb = *(const half8*)&Plds[g][w8][l][0];
            acc[g] = MFMA16(a4, pb, zc);
        }
        #pragma unroll
        for (int g = 0; g < 4; ++g) acc[g] = MFMA16(A0, breg[g][0], acc[g]);
        #pragma unroll
        for (int g = 0; g < 4; ++g) acc[g] = MFMA16(A1, breg[g][1], acc[g]);
        #pragma unroll
        for (int g = 0; g < 4; ++g) acc[g] = MFMA16(A2, breg[g][2], acc[g]);
        #pragma unroll
        for (int g = 0; g < 4; ++g) acc[g] = MFMA16(A3, breg[g][3], acc[g]);

        // ---- issue x(t+1) now: latency hides under the act chain ----
        float4 xv0, xv1;
        if (more) {
            xv0 = *(const float4*)(xp + (t + 1) * IDIM);
            xv1 = *(const float4*)(xp + (t + 1) * IDIM + o2);
        }

        // ---- act: 4 h per lane (rows mb..mb+3, col u) ----
        #pragma unroll
        for (int rp = 0; rp < 2; ++rp) {
            const int r0 = rp * 2, r1 = r0 + 1;
            f32x2 Ei = {EXP2F(acc[0][r0]), EXP2F(acc[0][r1])};   // e^{-i}
            f32x2 Ef = {EXP2F(acc[1][r0]), EXP2F(acc[1][r1])};   // e^{-f}
            f32x2 Eg = {EXP2F(acc[2][r0]), EXP2F(acc[2][r1])};   // e^{2g}
            f32x2 Eo = {EXP2F(acc[3][r0]), EXP2F(acc[3][r1])};   // e^{-o}
            f32x2 one = {1.f, 1.f};
            f32x2 Di = Ei + one, Df = Ef + one, Dg = Eg + one, Do = Eo + one;
            f32x2 Pif = Di * Df, Pgo = Dg * Do;
            f32x2 Rif = {RCPF(Pif.x), RCPF(Pif.y)};
            f32x2 Rgo = {RCPF(Pgo.x), RCPF(Pgo.y)};
            f32x2 is = Rif * Df, fs = Rif * Di;
            f32x2 gt = one - 2.f * (Rgo * Do);
            f32x2 os = Rgo * Dg;
            f32x2 cstp = rp ? cst23 : cst01;
            f32x2 c = fs * cstp + is * gt;
            if (rp) cst23 = c; else cst01 = c;
            f32x2 Etc = {EXP2F(c.x * P2LOG2E), EXP2F(c.y * P2LOG2E)};
            f32x2 Dtc = Etc + one;
            f32x2 Rtc = {RCPF(Dtc.x), RCPF(Dtc.y)};
            f32x2 tc = one - 2.f * Rtc;
            f32x2 h2 = os * tc;
            hv[r0] = h2.x; hv[r1] = h2.y;
        }

        if (more) {
            // h(t) -> the OTHER buffer's planes (read next step)
            #pragma unroll
            for (int r = 0; r < 4; ++r)
                nxt[kc_h][mb + r + 16 * quad][jh] = (_Float16)hv[r];
            cvt_a4(xv0, xv1);                  // a4 <- x(t+1) fragment
        }
        __syncthreads();
    }

    // ---- h(27) -> hplain (overlays Plds; all Plds reads are behind the
    //      final loop barrier) ----
    #pragma unroll
    for (int r = 0; r < 4; ++r)
        hplain[grp * 16 + mb + r][u] = hv[r];
    __syncthreads();

    // ---- FC + ReLU epilogue ----
    if (tid < TILE_B * CDIM) {
        int row = tid / CDIM, c = tid % CDIM;
        const float4* hv4 = (const float4*)&hplain[row][0];
        const float4* wf  = (const float4*)(Wfc + c * HDIM);
        float s = b_fc[c];
        #pragma unroll
        for (int q = 0; q < 32; ++q) {
            float4 a4v = hv4[q], b4 = wf[q];
            s += a4v.x * b4.x + a4v.y * b4.y + a4v.z * b4.z + a4v.w * b4.w;
        }
        out[(size_t)(b0 + row) * CDIM + c] = fmaxf(s, 0.f);
    }
}

extern "C" void kernel_launch(void* const* d_in, const int* in_sizes, int n_in,
                              void* d_out, int out_size, void* d_ws, size_t ws_size,
                              hipStream_t stream) {
    const float* x   = (const float*)d_in[0];
    const float* Wih = (const float*)d_in[1];
    const float* Whh = (const float*)d_in[2];
    const float* bih = (const float*)d_in[3];
    const float* bhh = (const float*)d_in[4];
    const float* Wfc = (const float*)d_in[5];
    const float* bfc = (const float*)d_in[6];
    float* out = (float*)d_out;
    _Float16* P = (_Float16*)d_ws;     // 160 KB packed weights

    hipLaunchKernelGGL(pack_w, dim3(320), dim3(256), 0, stream, Wih, Whh, bih, bhh, P);
    hipLaunchKernelGGL(lstm_kernel, dim3(8192 / TILE_B), dim3(1024), 0, stream,
                       x, P, Wfc, bfc, out);
}